// Round 5
// baseline (315.886 us; speedup 1.0000x reference)
//
#include <hip/hip_runtime.h>
#include <hip/hip_cooperative_groups.h>
#include <cstdint>
#include <cstddef>

namespace cg = cooperative_groups;

#define N_ANCH 25200
#define NB0 19200
#define NB1 24000
#define TOPK_N 4096
#define CONF_T 0.001
#define NMS_T 0.6
#define IMGS 640.0
#define NBINS 8192       // fp32 bits >> 17 (score in [0,1] -> bin < 8192)
#define GRID_B 256       // blocks; all co-resident (LDS 34KB -> 4 blocks/CU cap)
#define NTHR (GRID_B * 256)

typedef unsigned long long u64;

struct WS {
  alignas(64) double sc[N_ANCH];       // masked score (sc or -1.0)
  alignas(64) double box[N_ANCH][4];   // clipped normalized boxes, fp64
  alignas(64) int    cls[N_ANCH];
  alignas(64) int    binv[N_ANCH];     // score bin per anchor
  alignas(64) int    rank[N_ANCH];     // rank within subset (by subset position)
  alignas(64) int    subset[N_ANCH];   // anchor ids with bin >= t_bin
  alignas(64) double ssc[N_ANCH];      // packed scores of subset
  alignas(64) int    hist[NBINS];
  int    m_count;
  alignas(64) double tbox[TOPK_N][4];
  alignas(64) double tarea[TOPK_N];
  alignas(64) double tsc[TOPK_N];
  alignas(64) int    tcls[TOPK_N];
  alignas(64) u64    supT[TOPK_N * 64]; // supT[i*64+w] bit b: j=w*64+b suppresses i
  alignas(64) u64    hasSup[64];        // bit i of word (i>>6): row i has >=1 suppressor
};

__device__ __forceinline__ double dsigmoid(double x) { return 1.0 / (1.0 + exp(-x)); }

__device__ __forceinline__ int score_bin(double sc) {
  if (sc < 0.0) return 0;                          // masked
  return (int)(__float_as_uint((float)sc) >> 17);  // monotone for positive floats
}

struct SelSmem { int hist[NBINS]; int part[256]; };                 // 33792 B
struct RankSmem { double sj[2048]; int aj[2048]; };                 // 24576 B
struct IouSmem { double jb[64][5]; int jc[64]; };                   //  2816 B
struct NmsSmem { u64 hs[64]; int lst[TOPK_N]; };                    // 16896 B

__global__ void __launch_bounds__(256)
k_fused(const float* __restrict__ ps, const float* __restrict__ pm,
        const float* __restrict__ pl, const float* __restrict__ anch,
        WS* __restrict__ ws, float* __restrict__ out) {
  cg::grid_group grid = cg::this_grid();
  __shared__ union { SelSmem sel; RankSmem rk; IouSmem iou; NmsSmem nms; } sm;
  __shared__ int s_tbin;

  const int t = threadIdx.x;
  const int gtid = blockIdx.x * 256 + t;

  // ---------------- P1: init + decode (4 lanes per anchor) ----------------
  for (int b = gtid; b < NBINS; b += NTHR) ws->hist[b] = 0;
  if (gtid < 64) ws->hasSup[gtid] = 0ull;
  if (gtid == 64) ws->m_count = 0;

  for (int task = gtid; task < N_ANCH * 4; task += NTHR) {
    int a = task >> 2;
    int r = task & 3;
    const float* p; int W, base, lvl; double stride;
    if (a < NB0)      { p = ps; W = 80; base = 0;   lvl = 0; stride = 8.0; }
    else if (a < NB1) { p = pm; W = 40; base = NB0; lvl = 1; stride = 16.0; }
    else              { p = pl; W = 20; base = NB1; lvl = 2; stride = 32.0; }
    int e = a - base;
    int pos = e / 3;
    int k = e - 3 * pos;
    int HW = W * W;

    // class max/argmax + softmax denom, 20 classes per lane
    const float* pc = p + (size_t)(3 + k * 80) * HW + pos;
    double m = -1e300, ssum = 0.0; int am = 0;
    for (int u = 0; u < 20; ++u) {
      int c = r + 4 * u;
      double v = (double)pc[(size_t)c * HW];
      ssum += exp(v);
      if (v > m) { m = v; am = c; }
    }
    // team reduction across lanes r^1, r^2 (teams are 4-aligned within the wave)
    for (int off = 1; off <= 2; off <<= 1) {
      double om = __shfl_xor(m, off);
      int oam   = __shfl_xor(am, off);
      double os = __shfl_xor(ssum, off);
      ssum += os;
      if (om > m || (om == m && oam < am)) { m = om; am = oam; }
    }

    if (r == 0) {
      double sobj = dsigmoid((double)p[(size_t)k * HW + pos]);
      double sc = sobj * (exp(m) / ssum);

      int x = pos % W, y = pos / W;
      const float* pr = p + (size_t)(243 + k * 4) * HW + pos;
      double tx = (double)pr[0];
      double ty = (double)pr[(size_t)HW];
      double tw = (double)pr[(size_t)2 * HW];
      double th = (double)pr[(size_t)3 * HW];
      double cx = (dsigmoid(tx) + (double)x) * stride;
      double cy = (dsigmoid(ty) + (double)y) * stride;
      double aw = (double)anch[lvl * 6 + k * 2 + 0];
      double ah = (double)anch[lvl * 6 + k * 2 + 1];
      double bw = exp(tw) * aw;
      double bh = exp(th) * ah;
      double x1 = fmin(fmax((cx - 0.5 * bw) / IMGS, 0.0), 1.0);
      double y1 = fmin(fmax((cy - 0.5 * bh) / IMGS, 0.0), 1.0);
      double x2 = fmin(fmax((cx + 0.5 * bw) / IMGS, 0.0), 1.0);
      double y2 = fmin(fmax((cy + 0.5 * bh) / IMGS, 0.0), 1.0);

      ws->box[a][0] = x1; ws->box[a][1] = y1;
      ws->box[a][2] = x2; ws->box[a][3] = y2;
      ws->cls[a] = am;
      double scm = (sc >= CONF_T) ? sc : -1.0;
      ws->sc[a] = scm;
      ws->binv[a] = score_bin(scm);
    }
  }
  grid.sync();   // ---- sync1: binv/sc/box complete; hist/hasSup/m_count zeroed ----

  // ---------------- P2: histogram (per-block LDS, merge to global) --------
  for (int b = t; b < NBINS; b += 256) sm.sel.hist[b] = 0;
  __syncthreads();
  if (gtid < N_ANCH) atomicAdd(&sm.sel.hist[ws->binv[gtid]], 1);
  __syncthreads();
  for (int b = t; b < NBINS; b += 256) {
    int h = sm.sel.hist[b];
    if (h) atomicAdd(&ws->hist[b], h);
  }
  grid.sync();   // ---- sync2: global hist complete ----

  // ---------------- P3: t_bin (redundant per block) + compact -------------
  {
    const int CH = NBINS / 256;  // 32 reversed bins per thread
    int sum = 0;
    for (int rr = 0; rr < CH; ++rr) sum += ws->hist[NBINS - 1 - (t * CH + rr)];
    sm.sel.part[t] = sum;
    __syncthreads();
    for (int off = 1; off < 256; off <<= 1) {
      int v = (t >= off) ? sm.sel.part[t - off] : 0;
      __syncthreads();
      sm.sel.part[t] += v;
      __syncthreads();
    }
    int cum = sm.sel.part[t] - sum;  // count in bins above this thread's chunk
    for (int rr = 0; rr < CH; ++rr) {
      int b = NBINS - 1 - (t * CH + rr);
      int h = ws->hist[b];
      int prev = cum;
      cum += h;
      if (prev < TOPK_N && cum >= TOPK_N) s_tbin = b;  // unique crossing thread
    }
    __syncthreads();
    int tbin = s_tbin;
    if (gtid < N_ANCH) {
      if (ws->binv[gtid] >= tbin) {
        int idx = atomicAdd(&ws->m_count, 1);
        ws->subset[idx] = gtid;
        ws->ssc[idx] = ws->sc[gtid];
        ws->rank[idx] = 0;
      }
    }
  }
  grid.sync();   // ---- sync3: subset/ssc/rank-zero complete ----

  // ---------------- P4: exact rank within subset (16x16 block tiles) ------
  {
    int m = ws->m_count;
    int bi = blockIdx.x >> 4;   // 0..15 : i-tile
    int bj = blockIdx.x & 15;   // 0..15 : j-slice
    int jlen = (m + 15) >> 4;
    int j0 = bj * jlen;
    int jend = min(m, j0 + jlen);
    int i0 = bi * 256 + t, i1 = i0 + 4096, i2 = i1 + 4096;
    bool a0 = i0 < m, a1 = i1 < m, a2 = i2 < m;
    double s0 = a0 ? ws->ssc[i0] : 0.0;  int x0 = a0 ? ws->subset[i0] : 0;
    double s1 = a1 ? ws->ssc[i1] : 0.0;  int x1 = a1 ? ws->subset[i1] : 0;
    double s2 = a2 ? ws->ssc[i2] : 0.0;  int x2 = a2 ? ws->subset[i2] : 0;
    bool p1 = (m > 4096), p2 = (m > 8192);   // block-uniform
    int c0 = 0, c1 = 0, c2 = 0;
    for (int jc = j0; jc < jend; jc += 2048) {
      int n = min(2048, jend - jc);
      __syncthreads();
      for (int u = t; u < n; u += 256) {
        sm.rk.sj[u] = ws->ssc[jc + u];
        sm.rk.aj[u] = ws->subset[jc + u];
      }
      __syncthreads();
      for (int u = 0; u < n; ++u) {
        double s = sm.rk.sj[u]; int aa = sm.rk.aj[u];
        c0 += (int)((s > s0) | ((s == s0) & (aa < x0)));
      }
      if (p1) for (int u = 0; u < n; ++u) {
        double s = sm.rk.sj[u]; int aa = sm.rk.aj[u];
        c1 += (int)((s > s1) | ((s == s1) & (aa < x1)));
      }
      if (p2) for (int u = 0; u < n; ++u) {
        double s = sm.rk.sj[u]; int aa = sm.rk.aj[u];
        c2 += (int)((s > s2) | ((s == s2) & (aa < x2)));
      }
    }
    if (a0 && c0) atomicAdd(&ws->rank[i0], c0);
    if (a1 && c1) atomicAdd(&ws->rank[i1], c1);
    if (a2 && c2) atomicAdd(&ws->rank[i2], c2);
  }
  grid.sync();   // ---- sync4: ranks complete ----

  // ---------------- P5: scatter to rank-ordered arrays + out --------------
  {
    int m = ws->m_count;
    for (int i = gtid; i < m; i += NTHR) {
      int r = ws->rank[i];
      if (r < TOPK_N) {
        int a = ws->subset[i];
        double b0 = ws->box[a][0], b1 = ws->box[a][1];
        double b2 = ws->box[a][2], b3 = ws->box[a][3];
        double s  = ws->ssc[i];
        int    c  = ws->cls[a];
        ws->tbox[r][0] = b0; ws->tbox[r][1] = b1;
        ws->tbox[r][2] = b2; ws->tbox[r][3] = b3;
        ws->tarea[r] = (b2 - b0) * (b3 - b1);
        ws->tsc[r] = s;
        ws->tcls[r] = c;
        out[r * 4 + 0] = (float)b0;
        out[r * 4 + 1] = (float)b1;
        out[r * 4 + 2] = (float)b2;
        out[r * 4 + 3] = (float)b3;
        out[4 * TOPK_N + r] = (float)s;
        out[5 * TOPK_N + r] = (float)c;
      }
    }
  }
  grid.sync();   // ---- sync5: tbox/tarea/tsc/tcls complete ----

  // ---------------- P6: suppression matrix (1024 tiles, grid-stride) ------
  for (int tile = blockIdx.x; tile < 16 * 64; tile += GRID_B) {
    int ti = tile >> 6, w = tile & 63;
    int i0b = ti * 256, jbase = w * 64;
    int i = i0b + t;
    if (jbase >= i0b + 256) {                 // block-uniform: all j > i in tile
      ws->supT[(size_t)i * 64 + w] = 0ull;
      continue;
    }
    __syncthreads();                          // protect jb reuse across tiles
    if (t < 64) {
      int j = jbase + t;
      sm.iou.jb[t][0] = ws->tbox[j][0];
      sm.iou.jb[t][1] = ws->tbox[j][1];
      sm.iou.jb[t][2] = ws->tbox[j][2];
      sm.iou.jb[t][3] = ws->tbox[j][3];
      sm.iou.jb[t][4] = ws->tarea[j];
      sm.iou.jc[t] = ws->tcls[j];
    }
    __syncthreads();
    double x1 = ws->tbox[i][0], y1 = ws->tbox[i][1];
    double x2 = ws->tbox[i][2], y2 = ws->tbox[i][3];
    double ai = ws->tarea[i];
    int ci = ws->tcls[i];
    u64 bits = 0;
    for (int u = 0; u < 64; ++u) {
      double xx1 = fmax(x1, sm.iou.jb[u][0]);
      double yy1 = fmax(y1, sm.iou.jb[u][1]);
      double xx2 = fmin(x2, sm.iou.jb[u][2]);
      double yy2 = fmin(y2, sm.iou.jb[u][3]);
      double iw = fmax(1e-28, xx2 - xx1);
      double ih = fmax(1e-28, yy2 - yy1);
      double inter = iw * ih;
      double denom = ai + sm.iou.jb[u][4] - inter + 1e-14;
      bool sup = (sm.iou.jc[u] == ci) && (inter > NMS_T * denom) && ((jbase + u) < i);
      bits |= ((u64)sup) << u;
    }
    ws->supT[(size_t)i * 64 + w] = bits;
    if (bits) atomicOr(&ws->hasSup[i >> 6], 1ull << (i & 63));
  }
  grid.sync();   // ---- sync6: supT/hasSup complete ----

  // ---------------- P7: greedy NMS over contested candidates (block 0) ----
  if (blockIdx.x == 0) {
    u64 validw = 0, keepw = 0, hasw = 0;
    if (t < 64) {
      const double4* tp = (const double4*)(ws->tsc + t * 64);
      for (int q = 0; q < 16; ++q) {
        double4 v = tp[q];
        validw |= ((u64)(v.x >= CONF_T)) << (q * 4 + 0);
        validw |= ((u64)(v.y >= CONF_T)) << (q * 4 + 1);
        validw |= ((u64)(v.z >= CONF_T)) << (q * 4 + 2);
        validw |= ((u64)(v.w >= CONF_T)) << (q * 4 + 3);
      }
      hasw = ws->hasSup[t];
      keepw = validw & ~hasw;   // bulk-keep uncontested valid candidates
      sm.nms.hs[t] = hasw;
    }
    __syncthreads();
    int K = 0;
    if (t < 64) {
      for (int l = 0; l < 64; ++l) {
        u64 w = sm.nms.hs[l];
        while (w) {
          int b = __builtin_ctzll(w);
          w &= w - 1;
          if (t == 0) sm.nms.lst[K] = l * 64 + b;
          ++K;
        }
      }
    }
    __syncthreads();
    if (t < 64) {
      const u64* ST = ws->supT;
      const int* lst = sm.nms.lst;
      int IA[16], IB[16];
      u64 A[16], B[16];
#pragma unroll
      for (int r = 0; r < 16; ++r) IA[r] = (r < K) ? lst[r] : 0;
#pragma unroll
      for (int r = 0; r < 16; ++r) A[r] = (r < K) ? ST[(size_t)IA[r] * 64 + t] : 0ull;

      for (int base = 0; base < K; base += 32) {
#pragma unroll
        for (int r = 0; r < 16; ++r) IB[r] = (base + 16 + r < K) ? lst[base + 16 + r] : 0;
#pragma unroll
        for (int r = 0; r < 16; ++r) B[r] = (base + 16 + r < K) ? ST[(size_t)IB[r] * 64 + t] : 0ull;
#pragma unroll
        for (int r = 0; r < 16; ++r) {
          if (base + r < K) {
            int i = IA[r];
            u64 bal = __ballot((keepw & A[r]) != 0ull);
            if (t == (i >> 6) && bal == 0ull && ((validw >> (i & 63)) & 1ull))
              keepw |= 1ull << (i & 63);
          }
        }
#pragma unroll
        for (int r = 0; r < 16; ++r) IA[r] = (base + 32 + r < K) ? lst[base + 32 + r] : 0;
#pragma unroll
        for (int r = 0; r < 16; ++r) A[r] = (base + 32 + r < K) ? ST[(size_t)IA[r] * 64 + t] : 0ull;
#pragma unroll
        for (int r = 0; r < 16; ++r) {
          if (base + 16 + r < K) {
            int i = IB[r];
            u64 bal = __ballot((keepw & B[r]) != 0ull);
            if (t == (i >> 6) && bal == 0ull && ((validw >> (i & 63)) & 1ull))
              keepw |= 1ull << (i & 63);
          }
        }
      }
      for (int b = 0; b < 64; ++b)
        out[6 * TOPK_N + t * 64 + b] = (float)((keepw >> b) & 1ull);
    }
  }
}

extern "C" void kernel_launch(void* const* d_in, const int* in_sizes, int n_in,
                              void* d_out, int out_size, void* d_ws, size_t ws_size,
                              hipStream_t stream) {
  const float* ps   = (const float*)d_in[0];
  const float* pm   = (const float*)d_in[1];
  const float* pl   = (const float*)d_in[2];
  const float* anch = (const float*)d_in[3];
  float* out = (float*)d_out;
  WS* ws = (WS*)d_ws;

  void* args[] = { (void*)&ps, (void*)&pm, (void*)&pl, (void*)&anch, (void*)&ws, (void*)&out };
  hipLaunchCooperativeKernel((void*)k_fused, dim3(GRID_B), dim3(256), args, 0, stream);
}

// Round 6
// 232.810 us; speedup vs baseline: 1.3568x; 1.3568x over previous
//
#include <hip/hip_runtime.h>
#include <cstdint>
#include <cstddef>

#define N_ANCH 25200
#define NB0 19200
#define NB1 24000
#define TOPK_N 4096
#define CONF_T 0.001
#define NMS_T 0.6
#define IMGS 640.0
#define NBINS 8192       // fp32 bits >> 17 (score in [0,1] -> bin < 8192)

typedef unsigned long long u64;

struct WS {
  alignas(64) double sc[N_ANCH];       // masked score (sc or -1.0)
  alignas(64) double box[N_ANCH][4];   // clipped normalized boxes, fp64
  alignas(64) int    cls[N_ANCH];
  alignas(64) int    binv[N_ANCH];     // score bin per anchor
  alignas(64) int    subset[N_ANCH];   // anchor ids with bin >= t_bin
  alignas(64) double ssc[N_ANCH];      // packed scores of subset
  int    m_count;
  alignas(64) double tbox[TOPK_N][4];
  alignas(64) double tarea[TOPK_N];
  alignas(64) double tsc[TOPK_N];
  alignas(64) int    tcls[TOPK_N];
  alignas(64) u64    supT[TOPK_N * 64]; // supT[i*64+w] bit b: j=w*64+b suppresses i
  alignas(64) u64    hasSup[64];        // bit i of word (i>>6): row i has >=1 suppressor
};

__device__ __forceinline__ double dsigmoid(double x) { return 1.0 / (1.0 + exp(-x)); }

__device__ __forceinline__ int score_bin(double sc) {
  if (sc < 0.0) return 0;                          // masked
  return (int)(__float_as_uint((float)sc) >> 17);  // monotone for positive floats
}

// 4 lanes per anchor: lane r of a team handles classes c ≡ r (mod 4).
__global__ void k_decode(const float* __restrict__ ps, const float* __restrict__ pm,
                         const float* __restrict__ pl, const float* __restrict__ anch,
                         WS* __restrict__ ws) {
  int tid = blockIdx.x * 256 + threadIdx.x;
  int a = tid >> 2;
  int r = tid & 3;
  if (a >= N_ANCH) return;   // team-uniform (4-aligned)
  const float* p; int W, base, lvl; double stride;
  if (a < NB0)      { p = ps; W = 80; base = 0;   lvl = 0; stride = 8.0; }
  else if (a < NB1) { p = pm; W = 40; base = NB0; lvl = 1; stride = 16.0; }
  else              { p = pl; W = 20; base = NB1; lvl = 2; stride = 32.0; }
  int e = a - base;
  int pos = e / 3;
  int k = e - 3 * pos;
  int HW = W * W;

  // class max/argmax + softmax denom, 20 classes per lane
  const float* pc = p + (size_t)(3 + k * 80) * HW + pos;
  double m = -1e300, ssum = 0.0; int am = 0;
  for (int t = 0; t < 20; ++t) {
    int c = r + 4 * t;
    double v = (double)pc[(size_t)c * HW];
    ssum += exp(v);
    if (v > m) { m = v; am = c; }  // strict > keeps first occurrence per lane
  }
  // team reduction (lanes r^1, r^2 are in the same 4-lane group within the wave)
  for (int off = 1; off <= 2; off <<= 1) {
    double om = __shfl_xor(m, off);
    int oam   = __shfl_xor(am, off);
    double os = __shfl_xor(ssum, off);
    ssum += os;
    if (om > m || (om == m && oam < am)) { m = om; am = oam; }  // first-max tie-break
  }

  if (r == 0) {
    double sobj = dsigmoid((double)p[(size_t)k * HW + pos]);
    double sc = sobj * (exp(m) / ssum);

    int x = pos % W, y = pos / W;
    const float* pr = p + (size_t)(243 + k * 4) * HW + pos;
    double tx = (double)pr[0];
    double ty = (double)pr[(size_t)HW];
    double tw = (double)pr[(size_t)2 * HW];
    double th = (double)pr[(size_t)3 * HW];
    double cx = (dsigmoid(tx) + (double)x) * stride;
    double cy = (dsigmoid(ty) + (double)y) * stride;
    double aw = (double)anch[lvl * 6 + k * 2 + 0];
    double ah = (double)anch[lvl * 6 + k * 2 + 1];
    double bw = exp(tw) * aw;
    double bh = exp(th) * ah;
    double x1 = fmin(fmax((cx - 0.5 * bw) / IMGS, 0.0), 1.0);
    double y1 = fmin(fmax((cy - 0.5 * bh) / IMGS, 0.0), 1.0);
    double x2 = fmin(fmax((cx + 0.5 * bw) / IMGS, 0.0), 1.0);
    double y2 = fmin(fmax((cy + 0.5 * bh) / IMGS, 0.0), 1.0);

    ws->box[a][0] = x1; ws->box[a][1] = y1;
    ws->box[a][2] = x2; ws->box[a][3] = y2;
    ws->cls[a] = am;
    double scm = (sc >= CONF_T) ? sc : -1.0;
    ws->sc[a] = scm;
    ws->binv[a] = score_bin(scm);
  }
}

// single block: LDS hist over binv -> t_bin = max b with #{bin >= b} >= TOPK_N,
// then compact subset (ids + packed scores). S(0) = N_ANCH >= TOPK_N always.
__global__ void __launch_bounds__(1024) k_selcomp(WS* __restrict__ ws) {
  __shared__ int hist[NBINS];   // 32 KB
  __shared__ int part[1024];
  __shared__ int s_tbin;
  int t = threadIdx.x;
  if (t == 0) ws->m_count = 0;
  if (t < 64) ws->hasSup[t] = 0ull;   // zero for k_iou's atomicOr
  for (int i = t; i < NBINS; i += 1024) hist[i] = 0;
  __syncthreads();
  for (int i = t; i < N_ANCH; i += 1024) atomicAdd(&hist[ws->binv[i]], 1);
  __syncthreads();
  const int CH = NBINS / 1024;  // 8 reversed bins per thread
  int sum = 0;
  for (int rr = 0; rr < CH; ++rr) sum += hist[NBINS - 1 - (t * CH + rr)];
  part[t] = sum;
  __syncthreads();
  for (int off = 1; off < 1024; off <<= 1) {
    int v = (t >= off) ? part[t - off] : 0;
    __syncthreads();
    part[t] += v;
    __syncthreads();
  }
  int cum = part[t] - sum;  // count in bins above this thread's chunk
  for (int rr = 0; rr < CH; ++rr) {
    int b = NBINS - 1 - (t * CH + rr);
    int h = hist[b];
    int prev = cum;
    cum += h;
    if (prev < TOPK_N && cum >= TOPK_N) s_tbin = b;  // unique crossing thread
  }
  __syncthreads();
  int tbin = s_tbin;
  for (int i = t; i < N_ANCH; i += 1024) {
    if (ws->binv[i] >= tbin) {
      int idx = atomicAdd(&ws->m_count, 1);
      ws->subset[idx] = i;
      ws->ssc[idx] = ws->sc[i];
    }
  }
}

// Each block computes the COMPLETE rank of its 256 i's (loops over all m j's via
// LDS chunks), then scatters those i's — rank is block-private, no atomics.
// rank[i] = #{ j : sc_j > sc_i or (sc_j==sc_i && aj<ai) }
__global__ void k_rankscatter(WS* __restrict__ ws, float* __restrict__ out) {
  const int CHUNK = 2048;
  __shared__ double sj[CHUNK];
  __shared__ int    aj[CHUNK];
  int m = ws->m_count;
  if ((int)blockIdx.x * 256 >= m) return;   // block-uniform exit
  int t = threadIdx.x;
  int i = blockIdx.x * 256 + t;
  bool active = (i < m);
  int ai = active ? ws->subset[i] : 0;
  double si = active ? ws->ssc[i] : -2.0;

  int cnt = 0;
  for (int jc = 0; jc < m; jc += CHUNK) {
    int n = min(CHUNK, m - jc);
    __syncthreads();
    for (int u = t; u < n; u += 256) {
      aj[u] = ws->subset[jc + u];
      sj[u] = ws->ssc[jc + u];
    }
    __syncthreads();
    if (active) {
      for (int u = 0; u < n; ++u) {
        double s = sj[u];
        cnt += (int)((s > si) | ((s == si) & (aj[u] < ai)));
      }
    }
  }
  if (active && cnt < TOPK_N) {
    int r = cnt;
    double b0 = ws->box[ai][0], b1 = ws->box[ai][1];
    double b2 = ws->box[ai][2], b3 = ws->box[ai][3];
    int    c  = ws->cls[ai];
    ws->tbox[r][0] = b0; ws->tbox[r][1] = b1;
    ws->tbox[r][2] = b2; ws->tbox[r][3] = b3;
    ws->tarea[r] = (b2 - b0) * (b3 - b1);
    ws->tsc[r] = si;
    ws->tcls[r] = c;
    out[r * 4 + 0] = (float)b0;
    out[r * 4 + 1] = (float)b1;
    out[r * 4 + 2] = (float)b2;
    out[r * 4 + 3] = (float)b3;
    out[4 * TOPK_N + r] = (float)si;
    out[5 * TOPK_N + r] = (float)c;
  }
}

// supT[i*64+w]: bit t set iff j=w*64+t suppresses i (same class, iou>0.6, j<i).
// Upper-triangle blocks (all j >= i) write zeros without computing.
__global__ void k_iou(WS* __restrict__ ws) {
  int tid = threadIdx.x;
  int w = blockIdx.y;
  int i0 = blockIdx.x * 256;
  int jbase = w * 64;
  if (jbase >= i0 + 256) {                       // block-uniform: whole block is j > i
    ws->supT[(size_t)(i0 + tid) * 64 + w] = 0ull;
    return;
  }
  __shared__ double jb[64][5];
  __shared__ int jc[64];
  if (tid < 64) {
    int j = jbase + tid;
    jb[tid][0] = ws->tbox[j][0];
    jb[tid][1] = ws->tbox[j][1];
    jb[tid][2] = ws->tbox[j][2];
    jb[tid][3] = ws->tbox[j][3];
    jb[tid][4] = ws->tarea[j];
    jc[tid] = ws->tcls[j];
  }
  __syncthreads();
  int i = i0 + tid;
  double x1 = ws->tbox[i][0], y1 = ws->tbox[i][1];
  double x2 = ws->tbox[i][2], y2 = ws->tbox[i][3];
  double ai = ws->tarea[i];
  int ci = ws->tcls[i];
  u64 bits = 0;
  for (int t = 0; t < 64; ++t) {
    double xx1 = fmax(x1, jb[t][0]);
    double yy1 = fmax(y1, jb[t][1]);
    double xx2 = fmin(x2, jb[t][2]);
    double yy2 = fmin(y2, jb[t][3]);
    double iw = fmax(1e-28, xx2 - xx1);
    double ih = fmax(1e-28, yy2 - yy1);
    double inter = iw * ih;
    double denom = ai + jb[t][4] - inter + 1e-14;
    bool sup = (jc[t] == ci) && (inter > NMS_T * denom) && ((jbase + t) < i);
    bits |= ((u64)sup) << t;
  }
  ws->supT[(size_t)i * 64 + w] = bits;
  if (bits) atomicOr(&ws->hasSup[i >> 6], 1ull << (i & 63));
}

// single-wave greedy scan over CONTESTED candidates only (see R2 notes).
__global__ void __launch_bounds__(64) k_nms(const WS* __restrict__ ws, float* __restrict__ out) {
  __shared__ u64 hsArr[64];
  __shared__ int lst[TOPK_N];
  int lane = threadIdx.x;

  u64 validw = 0;
  const double4* tp = (const double4*)(ws->tsc + lane * 64);
  for (int q = 0; q < 16; ++q) {
    double4 v = tp[q];
    validw |= ((u64)(v.x >= CONF_T)) << (q * 4 + 0);
    validw |= ((u64)(v.y >= CONF_T)) << (q * 4 + 1);
    validw |= ((u64)(v.z >= CONF_T)) << (q * 4 + 2);
    validw |= ((u64)(v.w >= CONF_T)) << (q * 4 + 3);
  }

  u64 hasw = ws->hasSup[lane];
  u64 keepw = validw & ~hasw;   // bulk-keep uncontested valid candidates
  hsArr[lane] = hasw;
  __syncthreads();

  int K = 0;
  for (int l = 0; l < 64; ++l) {
    u64 w = hsArr[l];
    while (w) {
      int b = __builtin_ctzll(w);
      w &= w - 1;
      if (lane == 0) lst[K] = l * 64 + b;
      ++K;
    }
  }
  __syncthreads();

  const u64* ST = ws->supT;
  int IA[16], IB[16];
  u64 A[16], B[16];

#pragma unroll
  for (int r = 0; r < 16; ++r) IA[r] = (r < K) ? lst[r] : 0;
#pragma unroll
  for (int r = 0; r < 16; ++r) A[r] = (r < K) ? ST[(size_t)IA[r] * 64 + lane] : 0ull;

  for (int base = 0; base < K; base += 32) {
#pragma unroll
    for (int r = 0; r < 16; ++r) IB[r] = (base + 16 + r < K) ? lst[base + 16 + r] : 0;
#pragma unroll
    for (int r = 0; r < 16; ++r) B[r] = (base + 16 + r < K) ? ST[(size_t)IB[r] * 64 + lane] : 0ull;
#pragma unroll
    for (int r = 0; r < 16; ++r) {
      if (base + r < K) {
        int i = IA[r];
        u64 bal = __ballot((keepw & A[r]) != 0ull);
        if (lane == (i >> 6) && bal == 0ull && ((validw >> (i & 63)) & 1ull))
          keepw |= 1ull << (i & 63);
      }
    }
#pragma unroll
    for (int r = 0; r < 16; ++r) IA[r] = (base + 32 + r < K) ? lst[base + 32 + r] : 0;
#pragma unroll
    for (int r = 0; r < 16; ++r) A[r] = (base + 32 + r < K) ? ST[(size_t)IA[r] * 64 + lane] : 0ull;
#pragma unroll
    for (int r = 0; r < 16; ++r) {
      if (base + 16 + r < K) {
        int i = IB[r];
        u64 bal = __ballot((keepw & B[r]) != 0ull);
        if (lane == (i >> 6) && bal == 0ull && ((validw >> (i & 63)) & 1ull))
          keepw |= 1ull << (i & 63);
      }
    }
  }

  for (int b = 0; b < 64; ++b)
    out[6 * TOPK_N + lane * 64 + b] = (float)((keepw >> b) & 1ull);
}

extern "C" void kernel_launch(void* const* d_in, const int* in_sizes, int n_in,
                              void* d_out, int out_size, void* d_ws, size_t ws_size,
                              hipStream_t stream) {
  const float* ps   = (const float*)d_in[0];
  const float* pm   = (const float*)d_in[1];
  const float* pl   = (const float*)d_in[2];
  const float* anch = (const float*)d_in[3];
  float* out = (float*)d_out;
  WS* ws = (WS*)d_ws;

  dim3 blk(256);
  k_decode     <<<dim3((N_ANCH * 4 + 255) / 256), blk, 0, stream>>>(ps, pm, pl, anch, ws);
  k_selcomp    <<<dim3(1), dim3(1024), 0, stream>>>(ws);
  k_rankscatter<<<dim3((N_ANCH + 255) / 256), blk, 0, stream>>>(ws, out);
  k_iou        <<<dim3(TOPK_N / 256, 64), blk, 0, stream>>>(ws);
  k_nms        <<<dim3(1), dim3(64), 0, stream>>>(ws, out);
}